// Round 2
// baseline (145.884 us; speedup 1.0000x reference)
//
#include <hip/hip_runtime.h>
#include <stdint.h>

#define N_BOX 1024
#define C_CLS 80
#define B_IMG 4
#define K_PER 100
#define K_TOT 300
#define NEGF  (-1e30f)
#define NCAND (C_CLS * K_PER)    // 8000 candidates per image
#define M_SEL 8192               // flat-index packing base for final top-k
#define KPAD  1088               // 1024 + 64 swizzle pad

// workspace layout (bytes) — unchanged proven footprint; masks/scoresT slots
// now unused (prep_kernel eliminated r16: IoU computed on-the-fly in greedy)
#define OFF_WSCORE  1835008     // [B*C][K_PER] f32         128,000
#define OFF_WSIDX   1963008     // [B*C][K_PER] i32         128,000

typedef unsigned long long u64;
typedef unsigned int u32;

// LDS bank swizzle for u64 key array: bank16 rotates per 16-element group.
__device__ __forceinline__ int swz(int i) { return i + (i >> 4); }

// ---- monotone float <-> ordered-uint mapping (total order, bit-exact) ----
__device__ __forceinline__ u32 ford(float f) {
    u32 u = __float_as_uint(f);
    return (u & 0x80000000u) ? ~u : (u | 0x80000000u);
}
__device__ __forceinline__ float funord(u32 o) {
    u32 u = (o & 0x80000000u) ? (o ^ 0x80000000u) : ~o;
    return __uint_as_float(u);
}

// ---------------------------------------------------------------------------
// Kernel 1 (r16: fully fused sort+greedy, prep_kernel ELIMINATED): one block
// per (image, class-PAIR), 512 thr.
//  - boxes canonicalized once into LDS (shared by both halves)
//  - scores read directly with stride-C scalar loads (L2-resident; kills the
//    transpose kernel half)
//  - greedy computes IoU on the fly: per window a 64x64 kill matrix in pure
//    VALU (LDS broadcast reads), plus a <=kept-long check vs the kept-box
//    list for cross-window suppression. Bit-identical formulas (contract off,
//    IEEE division) to the old precomputed-mask path, which kills the
//    1024x1024 mask matrix (99% of it was never touched: greedy stops after
//    ~3 windows) and the whole prep launch + cross-XCD mask round-trip.
// ---------------------------------------------------------------------------
__global__ __launch_bounds__(512, 2) void nms_classes(
        const float* __restrict__ scores,   // [B, N, C]
        const float* __restrict__ boxes,    // [B, N, 1, 4]
        float* __restrict__ ws_score,       // [B*C*K_PER]
        int*   __restrict__ ws_idx)         // [B*C*K_PER]
{
    __shared__ u64    key[2][KPAD];         // 17408 B (swizzled)
    __shared__ float4 bx[N_BOX];            // canonical y1,x1,y2,x2 (16 KB)
    __shared__ float  ar[N_BOX];            // area (4 KB)
    __shared__ float4 wb[2][64];            // window candidate boxes (2 KB)
    __shared__ float  wa[2][64];            // window candidate areas (512 B)
    __shared__ float4 kb[2][K_PER];         // kept boxes (3.2 KB)
    __shared__ float  ka[2][K_PER];         // kept areas (800 B)
    __shared__ int    kept_t[2][K_PER];
    __shared__ int    sh_nvalid[2], sh_kept[2];

    const int tid  = threadIdx.x;
    const int half = tid >> 8;              // 0/1 = which class of the pair
    const int lt   = tid & 255;             // half-local thread id
    const int lane = tid & 63;
    const int b  = blockIdx.x / (C_CLS / 2);
    const int c  = (blockIdx.x % (C_CLS / 2)) * 2 + half;

    if (lt == 0) { sh_nvalid[half] = 0; sh_kept[half] = 0; }

    // ---- canonical boxes + areas into LDS (all 512 threads, image-level) ----
    for (int n = tid; n < N_BOX; n += 512) {
        float4 v = ((const float4*)boxes)[b * N_BOX + n];
        {
#pragma clang fp contract(off)
            float y1 = fminf(v.x, v.z), y2 = fmaxf(v.x, v.z);
            float x1 = fminf(v.y, v.w), x2 = fmaxf(v.y, v.w);
            bx[n] = make_float4(y1, x1, y2, x2);
            ar[n] = (y2 - y1) * (x2 - x1);
        }
    }
    __syncthreads();

    // ---- load scores: strided scalar reads (L2-resident, latency-batched) ----
    u64 r[4];
    {
        const float* sc = scores + (size_t)(b * N_BOX) * C_CLS + c;
        int lv = 0;
        #pragma unroll
        for (int q = 0; q < 4; ++q) {
            int v = lt * 4 + q;
            float s0 = sc[(size_t)v * C_CLS];
            bool valid = s0 > 0.001f;                  // SCORE_THR
            float s = valid ? s0 : NEGF;
            r[q] = ((u64)ford(s) << 32) | (u32)(N_BOX - 1 - v);  // stable ties
            lv += valid ? 1 : 0;
        }
        if (lv) atomicAdd(&sh_nvalid[half], lv);
    }

    // ---- register/shuffle bitonic sort, descending (proven network) ----
    #define CE(a, b, d) { u64 _mx = (a) > (b) ? (a) : (b); \
                          u64 _mn = (a) > (b) ? (b) : (a); \
                          (a) = (d) ? _mx : _mn; (b) = (d) ? _mn : _mx; }
    CE(r[0], r[1], true); CE(r[2], r[3], false);

    for (int k = 4; k <= N_BOX; k <<= 1) {
        const bool d = ((lt & (k >> 2)) == 0);
        for (int j = k >> 1; j > 0; j >>= 1) {
            if (j >= 256) {                          // cross-wave: LDS stage
                __syncthreads();
                #pragma unroll
                for (int q = 0; q < 4; ++q) key[half][swz(lt * 4 + q)] = r[q];
                __syncthreads();
                const bool upper = ((lt * 4) & j) != 0;
                #pragma unroll
                for (int q = 0; q < 4; ++q) {
                    u64 pv = key[half][swz((lt * 4 + q) ^ j)];
                    u64 mx = r[q] > pv ? r[q] : pv;
                    u64 mn = r[q] > pv ? pv : r[q];
                    r[q] = (d != upper) ? mx : mn;
                }
            } else if (j >= 4) {                     // intra-wave: shuffle
                const int dl = j >> 2;
                const bool upper = (lane & dl) != 0;
                #pragma unroll
                for (int q = 0; q < 4; ++q) {
                    u64 pv = __shfl_xor(r[q], dl);
                    u64 mx = r[q] > pv ? r[q] : pv;
                    u64 mn = r[q] > pv ? pv : r[q];
                    r[q] = (d != upper) ? mx : mn;
                }
            } else if (j == 2) {
                CE(r[0], r[2], d); CE(r[1], r[3], d);
            } else {
                CE(r[0], r[1], d); CE(r[2], r[3], d);
            }
        }
    }
    #undef CE

    __syncthreads();
    #pragma unroll
    for (int q = 0; q < 4; ++q) key[half][swz(lt * 4 + q)] = r[q];
    __syncthreads();

    // ---- greedy with on-the-fly IoU: wave 0 -> half 0, wave 4 -> half 1 ----
    const int wv = tid >> 6;
    if (wv == 0 || wv == 4) {
        const int gh = wv >> 2;
        const int nvalid = sh_nvalid[gh];
        const int nwin = (nvalid + 63) >> 6;    // windows actually populated
        int kept = 0;

        for (int w = 0; w < nwin && kept < K_PER; ++w) {
            const int bt = w * 64;
            const int t = bt + lane;
            const bool in = t < nvalid;
            u64 kv = key[gh][swz(t & (N_BOX - 1))];
            int idx = (N_BOX - 1) - (int)(u32)(kv & 0xFFFFFFFFu);
            const float4 q4 = bx[idx];
            const float  aq = ar[idx];

            // cross-window suppression: vs all previously-kept boxes
            bool alive = in;
            for (int k = 0; k < kept; ++k) {
                float4 p = kb[gh][k];               // LDS broadcast
                float ap = ka[gh][k];
                {
#pragma clang fp contract(off)
                    float ih = fminf(p.z, q4.z) - fmaxf(p.x, q4.x); ih = fmaxf(ih, 0.0f);
                    float iw = fminf(p.w, q4.w) - fmaxf(p.y, q4.y); iw = fmaxf(iw, 0.0f);
                    float inter = ih * iw;
                    float uni = fmaxf(ap + aq - inter, 1e-12f);
                    if ((inter / uni) > 0.5f) alive = false;
                }
            }
            u64 pending = __ballot(alive);
            if (!pending) continue;

            // intra-window 64x64 kill matrix (LDS broadcast, pure VALU)
            wb[gh][lane] = q4; wa[gh][lane] = aq;
            __builtin_amdgcn_wave_barrier();
            u64 kill_mask = 0;                      // bit rr: candidate rr kills me
            for (int rr = 0; rr < 64; ++rr) {
                float4 p = wb[gh][rr];              // broadcast read
                float ap = wa[gh][rr];
                bool kill;
                {
#pragma clang fp contract(off)
                    float ih = fminf(p.z, q4.z) - fmaxf(p.x, q4.x); ih = fmaxf(ih, 0.0f);
                    float iw = fminf(p.w, q4.w) - fmaxf(p.y, q4.y); iw = fmaxf(iw, 0.0f);
                    float inter = ih * iw;
                    float uni = fmaxf(ap + aq - inter, 1e-12f);
                    kill = (rr != lane) && ((inter / uni) > 0.5f);
                }
                kill_mask |= ((u64)kill) << rr;
            }

            // accept-only serial loop: pure VALU + ballot
            while (pending && kept < K_PER) {
                int t0 = __ffsll((long long)pending) - 1;      // wave-uniform
                if (lane == 0) kept_t[gh][kept] = bt + t0;
                if (lane == t0) { kb[gh][kept] = q4; ka[gh][kept] = aq; }
                kept++;
                bool kill = (kill_mask >> t0) & 1ull;
                pending &= ~(1ull << t0);
                pending &= ~__ballot(kill);
            }
        }
        if (lane == 0) sh_kept[gh] = kept;
    }
    __syncthreads();

    const int kept = sh_kept[half];
    if (lt < K_PER) {
        int ob = (b * C_CLS + c) * K_PER + lt;
        if (lt < kept) {
            u64 k = key[half][swz(kept_t[half][lt])];
            ws_score[ob] = funord((u32)(k >> 32));
            ws_idx[ob]   = (N_BOX - 1) - (int)(u32)(k & 0xFFFFFFFFu);
        } else {
            ws_score[ob] = NEGF;
            ws_idx[ob]   = 0;
        }
    }
}

// ---------------------------------------------------------------------------
// Kernel 2: final top-300 per image (proven verbatim).
// ---------------------------------------------------------------------------
__global__ __launch_bounds__(1024) void final_topk(
        const float* __restrict__ ws_score,
        const int*   __restrict__ ws_idx,
        const float* __restrict__ boxes,    // [B, N, 1, 4]
        float* __restrict__ out)
{
    __shared__ u32 skey[NCAND];             // 32 KB
    __shared__ u32 hist4[256 * 4];          // 4 KB
    __shared__ u64 list[512];
    __shared__ int sh_sel;
    __shared__ u32 sh_need;
    __shared__ int sh_cnt, sh_valid;

    const int tid = threadIdx.x;
    const int b = blockIdx.x;
    const int base = b * NCAND;

    if (tid == 0) { sh_cnt = 0; sh_valid = 0; }
    for (int i = tid; i < NCAND; i += 1024)
        skey[i] = ford(ws_score[base + i]);
    if (tid < 512) list[tid] = 0;
    hist4[tid] = 0;
    __syncthreads();

    u64 prefix = 0;
    u32 need = K_TOT;
    const int rounds[6] = {7, 6, 5, 4, 1, 0};
    const int slot = tid & 3;

    for (int rd = 0; rd < 6; ++rd) {
        const int d = rounds[rd];
        for (int i = tid; i < NCAND; i += 1024) {
            u64 k = ((u64)skey[i] << 32) | (u32)(M_SEL - 1 - i);
            // d==7 guard: shift by 64 is UB (the round-3/4 crash)
            bool match = (d == 7) || (((k ^ prefix) >> (8 * (d + 1))) == 0);
            if (match)
                atomicAdd(&hist4[(((u32)(k >> (8 * d)) & 0xFFu) << 2) | slot], 1u);
        }
        __syncthreads();
        if (tid < 64) {
            const int l = tid;
            u32 h[4];
            #pragma unroll
            for (int q = 0; q < 4; ++q) {
                int bin = 4 * l + q;
                h[q] = hist4[bin * 4 + 0] + hist4[bin * 4 + 1]
                     + hist4[bin * 4 + 2] + hist4[bin * 4 + 3];
                hist4[bin * 4 + 0] = 0; hist4[bin * 4 + 1] = 0;
                hist4[bin * 4 + 2] = 0; hist4[bin * 4 + 3] = 0;
            }
            u32 s3 = h[3], s2 = h[2] + s3, s1 = h[1] + s2, s0 = h[0] + s1;
            u32 tot = s0, S = tot;
            #pragma unroll
            for (int off = 1; off < 64; off <<= 1) {
                u32 t = __shfl(S, (l + off) & 63);
                if (l + off < 64) S += t;
            }
            u32 T = S - tot;
            u32 sv0 = s0 + T, sv1 = s1 + T, sv2 = s2 + T, sv3 = s3 + T;
            if (sv0 >= need && sv1 < need) { sh_sel = 4*l;     sh_need = need - sv1; }
            if (sv1 >= need && sv2 < need) { sh_sel = 4*l + 1; sh_need = need - sv2; }
            if (sv2 >= need && sv3 < need) { sh_sel = 4*l + 2; sh_need = need - sv3; }
            if (sv3 >= need && T   < need) { sh_sel = 4*l + 3; sh_need = need - T;   }
        }
        __syncthreads();
        prefix |= ((u64)(u32)sh_sel) << (8 * d);
        need = sh_need;
        __syncthreads();
    }

    for (int i = tid; i < NCAND; i += 1024) {
        u64 k = ((u64)skey[i] << 32) | (u32)(M_SEL - 1 - i);
        if (k >= prefix) {
            int p = atomicAdd(&sh_cnt, 1);
            if (p < 512) list[p] = k;
        }
    }
    __syncthreads();

    // one-wave register bitonic sort of list[512], descending (pads 0 last)
    if (tid < 64) {
        const int l = tid;
        u64 e[8];
        #pragma unroll
        for (int q = 0; q < 8; ++q) e[q] = list[l * 8 + q];
        #define CE2(a, b, dd) { u64 _mx = (a) > (b) ? (a) : (b); \
                                u64 _mn = (a) > (b) ? (b) : (a); \
                                (a) = (dd) ? _mx : _mn; (b) = (dd) ? _mn : _mx; }
        CE2(e[0], e[1], true);  CE2(e[2], e[3], false);
        CE2(e[4], e[5], true);  CE2(e[6], e[7], false);
        CE2(e[0], e[2], true);  CE2(e[1], e[3], true);
        CE2(e[4], e[6], false); CE2(e[5], e[7], false);
        CE2(e[0], e[1], true);  CE2(e[2], e[3], true);
        CE2(e[4], e[5], false); CE2(e[6], e[7], false);
        for (int k = 8; k <= 512; k <<= 1) {
            const bool d = ((l & (k >> 3)) == 0);
            for (int j = k >> 1; j >= 8; j >>= 1) {
                const int dl = j >> 3;
                const bool upper = (l & dl) != 0;
                #pragma unroll
                for (int q = 0; q < 8; ++q) {
                    u64 pv = __shfl_xor(e[q], dl);
                    u64 mx = e[q] > pv ? e[q] : pv;
                    u64 mn = e[q] > pv ? pv : e[q];
                    e[q] = (d != upper) ? mx : mn;
                }
            }
            CE2(e[0], e[4], d); CE2(e[1], e[5], d);
            CE2(e[2], e[6], d); CE2(e[3], e[7], d);
            CE2(e[0], e[2], d); CE2(e[1], e[3], d);
            CE2(e[4], e[6], d); CE2(e[5], e[7], d);
            CE2(e[0], e[1], d); CE2(e[2], e[3], d);
            CE2(e[4], e[5], d); CE2(e[6], e[7], d);
        }
        #undef CE2
        #pragma unroll
        for (int q = 0; q < 8; ++q) list[l * 8 + q] = e[q];
    }
    __syncthreads();

    float* out_s = out;                         // [B,300]
    float* out_b = out + B_IMG * K_TOT;         // [B,300,4]
    float* out_c = out + B_IMG * K_TOT * 5;     // [B,300]
    float* out_n = out + B_IMG * K_TOT * 6;     // [B]

    for (int i = tid; i < K_TOT; i += 1024) {
        u64 k = list[i];
        float s = funord((u32)(k >> 32));
        int flat = (M_SEL - 1) - (int)(u32)(k & 0xFFFFFFFFu);
        bool valid = s > (-5e29f);              // top_s > NEG/2
        float os = 0.0f, oc = 0.0f;
        float4 ob = make_float4(0.0f, 0.0f, 0.0f, 0.0f);
        if (valid && flat < NCAND) {
            int cc = flat / K_PER;
            int n  = ws_idx[base + flat];
            float4 bb = ((const float4*)boxes)[b * N_BOX + n];
            os = s;
            oc = (float)cc;
            ob.x = fminf(fmaxf(bb.x, 0.0f), 1.0f);
            ob.y = fminf(fmaxf(bb.y, 0.0f), 1.0f);
            ob.z = fminf(fmaxf(bb.z, 0.0f), 1.0f);
            ob.w = fminf(fmaxf(bb.w, 0.0f), 1.0f);
            atomicAdd(&sh_valid, 1);
        }
        out_s[b * K_TOT + i] = os;
        ((float4*)out_b)[b * K_TOT + i] = ob;
        out_c[b * K_TOT + i] = oc;
    }
    __syncthreads();
    if (tid == 0) out_n[b] = (float)sh_valid;
}

extern "C" void kernel_launch(void* const* d_in, const int* in_sizes, int n_in,
                              void* d_out, int out_size, void* d_ws, size_t ws_size,
                              hipStream_t stream) {
    const float* scores = (const float*)d_in[0];   // [4,1024,80]
    const float* boxes  = (const float*)d_in[1];   // [4,1024,1,4]

    char* ws = (char*)d_ws;                        // footprint unchanged
    float* ws_score = (float*)(ws + OFF_WSCORE);
    int*   ws_idx   = (int*)  (ws + OFF_WSIDX);

    nms_classes<<<dim3(B_IMG * (C_CLS / 2)), dim3(512), 0, stream>>>(
        scores, boxes, ws_score, ws_idx);
    final_topk<<<dim3(B_IMG), dim3(1024), 0, stream>>>(
        ws_score, ws_idx, boxes, (float*)d_out);
}

// Round 3
// 120.992 us; speedup vs baseline: 1.2057x; 1.2057x over previous
//
#include <hip/hip_runtime.h>
#include <stdint.h>

#define N_BOX 1024
#define C_CLS 80
#define B_IMG 4
#define K_PER 100
#define K_TOT 300
#define NEGF  (-1e30f)
#define NCAND (C_CLS * K_PER)    // 8000 candidates per image
#define M_SEL 8192               // flat-index packing base for final top-k
#define KPAD  1088               // 1024 + 64 swizzle pad

// workspace layout (bytes) — unchanged proven offsets
#define OFF_WSCORE  1835008     // [B*C][K_PER] f32         128,000
#define OFF_WSIDX   1963008     // [B*C][K_PER] i32         128,000

typedef unsigned long long u64;
typedef unsigned int u32;

// LDS bank swizzle for u64 key array: bank16 rotates per 16-element group.
__device__ __forceinline__ int swz(int i) { return i + (i >> 4); }

// ---- monotone float <-> ordered-uint mapping (total order, bit-exact) ----
__device__ __forceinline__ u32 ford(float f) {
    u32 u = __float_as_uint(f);
    return (u & 0x80000000u) ? ~u : (u | 0x80000000u);
}
__device__ __forceinline__ float funord(u32 o) {
    u32 u = (o & 0x80000000u) ? (o ^ 0x80000000u) : ~o;
    return __uint_as_float(u);
}

// exact reference IoU>0.5 test (contract off, IEEE divide — proven bit-exact)
__device__ __forceinline__ bool iou_gt(float4 a, float aa, float4 b, float ab) {
#pragma clang fp contract(off)
    float ih = fminf(a.z, b.z) - fmaxf(a.x, b.x); ih = fmaxf(ih, 0.0f);
    float iw = fminf(a.w, b.w) - fmaxf(a.y, b.y); iw = fmaxf(iw, 0.0f);
    float inter = ih * iw;
    float uni = fmaxf(aa + ab - inter, 1e-12f);
    return (inter / uni) > 0.5f;
}

// ---------------------------------------------------------------------------
// Kernel 1 (r17): one block per (image, class), 256 thr, 4 waves.
//  - proven 256-thread bitonic sort (register/shuffle + swizzled LDS stages)
//  - per-window suppression data (64-bit colkill + suppressed masks) built by
//    ALL 256 threads in parallel between windows (~40 IoUs/thread); the
//    greedy wave runs the r15-proven accept loop on pure bit ops — NO math
//    on the serial chain (the r16 mistake).
//  - no prep kernel, no 1024x1024 mask matrix, no HBM mask round-trip.
// ---------------------------------------------------------------------------
__global__ __launch_bounds__(256, 2) void nms_classes(
        const float* __restrict__ scores,   // [B, N, C]
        const float* __restrict__ boxes,    // [B, N, 1, 4]
        float* __restrict__ ws_score,       // [B*C*K_PER]
        int*   __restrict__ ws_idx)         // [B*C*K_PER]
{
    __shared__ u64    key[KPAD];            // 8704 B (swizzled)
    __shared__ float4 bx[N_BOX];            // canonical y1,x1,y2,x2 (16 KB)
    __shared__ float  ar[N_BOX];            // area (4 KB)
    __shared__ float4 kb[K_PER];            // kept boxes
    __shared__ float  ka[K_PER];            // kept areas
    __shared__ int    kept_t[K_PER];
    __shared__ u32    colk32[64][2];        // per-candidate who-kills-me mask
    __shared__ u32    suppw[2];             // suppressed-by-kept mask
    __shared__ int    sh_nvalid, sh_kept;

    const int tid  = threadIdx.x;
    const int lane = tid & 63;
    const int b  = blockIdx.x / C_CLS;
    const int c  = blockIdx.x % C_CLS;

    if (tid == 0) { sh_nvalid = 0; sh_kept = 0; }

    // ---- canonical boxes + areas into LDS ----
    for (int n = tid; n < N_BOX; n += 256) {
        float4 v = ((const float4*)boxes)[b * N_BOX + n];
        {
#pragma clang fp contract(off)
            float y1 = fminf(v.x, v.z), y2 = fmaxf(v.x, v.z);
            float x1 = fminf(v.y, v.w), x2 = fmaxf(v.y, v.w);
            bx[n] = make_float4(y1, x1, y2, x2);
            ar[n] = (y2 - y1) * (x2 - x1);
        }
    }
    __syncthreads();

    // ---- load scores: strided scalar reads (L2/L3-resident) ----
    u64 r[4];
    {
        const float* sc = scores + (size_t)(b * N_BOX) * C_CLS + c;
        int lv = 0;
        #pragma unroll
        for (int q = 0; q < 4; ++q) {
            int v = tid * 4 + q;
            float s0 = sc[(size_t)v * C_CLS];
            bool valid = s0 > 0.001f;                  // SCORE_THR
            float s = valid ? s0 : NEGF;
            r[q] = ((u64)ford(s) << 32) | (u32)(N_BOX - 1 - v);  // stable ties
            lv += valid ? 1 : 0;
        }
        if (lv) atomicAdd(&sh_nvalid, lv);
    }

    // ---- register/shuffle bitonic sort, descending (proven network) ----
    #define CE(a, b, d) { u64 _mx = (a) > (b) ? (a) : (b); \
                          u64 _mn = (a) > (b) ? (b) : (a); \
                          (a) = (d) ? _mx : _mn; (b) = (d) ? _mn : _mx; }
    CE(r[0], r[1], true); CE(r[2], r[3], false);

    for (int k = 4; k <= N_BOX; k <<= 1) {
        const bool d = ((tid & (k >> 2)) == 0);
        for (int j = k >> 1; j > 0; j >>= 1) {
            if (j >= 256) {                          // cross-wave: LDS stage
                __syncthreads();
                #pragma unroll
                for (int q = 0; q < 4; ++q) key[swz(tid * 4 + q)] = r[q];
                __syncthreads();
                const bool upper = ((tid * 4) & j) != 0;
                #pragma unroll
                for (int q = 0; q < 4; ++q) {
                    u64 pv = key[swz((tid * 4 + q) ^ j)];
                    u64 mx = r[q] > pv ? r[q] : pv;
                    u64 mn = r[q] > pv ? pv : r[q];
                    r[q] = (d != upper) ? mx : mn;
                }
            } else if (j >= 4) {                     // intra-wave: shuffle
                const int dl = j >> 2;
                const bool upper = (lane & dl) != 0;
                #pragma unroll
                for (int q = 0; q < 4; ++q) {
                    u64 pv = __shfl_xor(r[q], dl);
                    u64 mx = r[q] > pv ? r[q] : pv;
                    u64 mn = r[q] > pv ? pv : r[q];
                    r[q] = (d != upper) ? mx : mn;
                }
            } else if (j == 2) {
                CE(r[0], r[2], d); CE(r[1], r[3], d);
            } else {
                CE(r[0], r[1], d); CE(r[2], r[3], d);
            }
        }
    }
    #undef CE

    __syncthreads();
    #pragma unroll
    for (int q = 0; q < 4; ++q) key[swz(tid * 4 + q)] = r[q];
    __syncthreads();

    // ---- windowed greedy: parallel window prep + 1-wave bit-ops accept ----
    const int nvalid = sh_nvalid;
    const int nwin = (nvalid + 63) >> 6;
    const int me  = tid & 63;               // candidate slot in window
    const int grp = tid >> 6;               // 0..3 (wave id)

    for (int w = 0; w < nwin; ++w) {
        __syncthreads();                    // (A) prev window's kept stable
        if (sh_kept >= K_PER) break;        // uniform
        const int kept0 = sh_kept;
        const int bt = w * 64;

        // my candidate's box (all threads; grp-replicated)
        u64 kvm = key[swz((bt + me) & (N_BOX - 1))];
        int idxm = (N_BOX - 1) - (int)(u32)(kvm & 0xFFFFFFFFu);
        const float4 qm = bx[idxm];
        const float  am = ar[idxm];

        if (grp == 0) { colk32[me][0] = 0; colk32[me][1] = 0; }
        if (tid < 2) suppw[tid] = 0;
        __syncthreads();                    // (B) init visible

        // cross-window: me vs kept boxes, strided over 4 waves
        bool supme = false;
        for (int k = grp; k < kept0; k += 4)
            if (iou_gt(kb[k], ka[k], qm, am)) supme = true;
        if (supme) atomicOr(&suppw[me >> 5], 1u << (me & 31));

        // intra-window kill matrix: rows rr in [grp*16, grp*16+16)
        u32 bits = 0;
        #pragma unroll
        for (int rq = 0; rq < 16; ++rq) {
            int rr = grp * 16 + rq;
            u64 kvr = key[swz((bt + rr) & (N_BOX - 1))];
            int idxr = (N_BOX - 1) - (int)(u32)(kvr & 0xFFFFFFFFu);
            bool kill = (rr != me) && iou_gt(bx[idxr], ar[idxr], qm, am);
            bits |= ((u32)kill) << rq;
        }
        atomicOr(&colk32[me][grp >> 1], bits << ((grp & 1) * 16));
        __syncthreads();                    // (C) masks ready

        // greedy accept loop: wave 0 only, pure bit ops (r15-proven shape)
        if (grp == 0) {
            const u64 colkill = ((u64)colk32[lane][1] << 32) | colk32[lane][0];
            const u64 supp    = ((u64)suppw[1] << 32) | suppw[0];
            bool in = ((bt + lane) < nvalid) && !((supp >> lane) & 1ull);
            u64 pending = __ballot(in);
            int kept = kept0;
            while (pending && kept < K_PER) {
                int t0 = __ffsll((long long)pending) - 1;   // wave-uniform
                if (lane == 0) kept_t[kept] = bt + t0;
                if (lane == t0) { kb[kept] = qm; ka[kept] = am; }
                kept++;
                bool kill = (colkill >> t0) & 1ull;
                pending &= ~(1ull << t0);
                pending &= ~__ballot(kill);
            }
            if (lane == 0) sh_kept = kept;
        }
    }
    __syncthreads();

    const int kept = sh_kept;
    if (tid < K_PER) {
        int ob = (b * C_CLS + c) * K_PER + tid;
        if (tid < kept) {
            u64 k = key[swz(kept_t[tid])];
            ws_score[ob] = funord((u32)(k >> 32));
            ws_idx[ob]   = (N_BOX - 1) - (int)(u32)(k & 0xFFFFFFFFu);
        } else {
            ws_score[ob] = NEGF;
            ws_idx[ob]   = 0;
        }
    }
}

// ---------------------------------------------------------------------------
// Kernel 2: final top-300 per image (proven verbatim).
// ---------------------------------------------------------------------------
__global__ __launch_bounds__(1024) void final_topk(
        const float* __restrict__ ws_score,
        const int*   __restrict__ ws_idx,
        const float* __restrict__ boxes,    // [B, N, 1, 4]
        float* __restrict__ out)
{
    __shared__ u32 skey[NCAND];             // 32 KB
    __shared__ u32 hist4[256 * 4];          // 4 KB
    __shared__ u64 list[512];
    __shared__ int sh_sel;
    __shared__ u32 sh_need;
    __shared__ int sh_cnt, sh_valid;

    const int tid = threadIdx.x;
    const int b = blockIdx.x;
    const int base = b * NCAND;

    if (tid == 0) { sh_cnt = 0; sh_valid = 0; }
    for (int i = tid; i < NCAND; i += 1024)
        skey[i] = ford(ws_score[base + i]);
    if (tid < 512) list[tid] = 0;
    hist4[tid] = 0;
    __syncthreads();

    u64 prefix = 0;
    u32 need = K_TOT;
    const int rounds[6] = {7, 6, 5, 4, 1, 0};
    const int slot = tid & 3;

    for (int rd = 0; rd < 6; ++rd) {
        const int d = rounds[rd];
        for (int i = tid; i < NCAND; i += 1024) {
            u64 k = ((u64)skey[i] << 32) | (u32)(M_SEL - 1 - i);
            // d==7 guard: shift by 64 is UB (the round-3/4 crash)
            bool match = (d == 7) || (((k ^ prefix) >> (8 * (d + 1))) == 0);
            if (match)
                atomicAdd(&hist4[(((u32)(k >> (8 * d)) & 0xFFu) << 2) | slot], 1u);
        }
        __syncthreads();
        if (tid < 64) {
            const int l = tid;
            u32 h[4];
            #pragma unroll
            for (int q = 0; q < 4; ++q) {
                int bin = 4 * l + q;
                h[q] = hist4[bin * 4 + 0] + hist4[bin * 4 + 1]
                     + hist4[bin * 4 + 2] + hist4[bin * 4 + 3];
                hist4[bin * 4 + 0] = 0; hist4[bin * 4 + 1] = 0;
                hist4[bin * 4 + 2] = 0; hist4[bin * 4 + 3] = 0;
            }
            u32 s3 = h[3], s2 = h[2] + s3, s1 = h[1] + s2, s0 = h[0] + s1;
            u32 tot = s0, S = tot;
            #pragma unroll
            for (int off = 1; off < 64; off <<= 1) {
                u32 t = __shfl(S, (l + off) & 63);
                if (l + off < 64) S += t;
            }
            u32 T = S - tot;
            u32 sv0 = s0 + T, sv1 = s1 + T, sv2 = s2 + T, sv3 = s3 + T;
            if (sv0 >= need && sv1 < need) { sh_sel = 4*l;     sh_need = need - sv1; }
            if (sv1 >= need && sv2 < need) { sh_sel = 4*l + 1; sh_need = need - sv2; }
            if (sv2 >= need && sv3 < need) { sh_sel = 4*l + 2; sh_need = need - sv3; }
            if (sv3 >= need && T   < need) { sh_sel = 4*l + 3; sh_need = need - T;   }
        }
        __syncthreads();
        prefix |= ((u64)(u32)sh_sel) << (8 * d);
        need = sh_need;
        __syncthreads();
    }

    for (int i = tid; i < NCAND; i += 1024) {
        u64 k = ((u64)skey[i] << 32) | (u32)(M_SEL - 1 - i);
        if (k >= prefix) {
            int p = atomicAdd(&sh_cnt, 1);
            if (p < 512) list[p] = k;
        }
    }
    __syncthreads();

    // one-wave register bitonic sort of list[512], descending (pads 0 last)
    if (tid < 64) {
        const int l = tid;
        u64 e[8];
        #pragma unroll
        for (int q = 0; q < 8; ++q) e[q] = list[l * 8 + q];
        #define CE2(a, b, dd) { u64 _mx = (a) > (b) ? (a) : (b); \
                                u64 _mn = (a) > (b) ? (b) : (a); \
                                (a) = (dd) ? _mx : _mn; (b) = (dd) ? _mn : _mx; }
        CE2(e[0], e[1], true);  CE2(e[2], e[3], false);
        CE2(e[4], e[5], true);  CE2(e[6], e[7], false);
        CE2(e[0], e[2], true);  CE2(e[1], e[3], true);
        CE2(e[4], e[6], false); CE2(e[5], e[7], false);
        CE2(e[0], e[1], true);  CE2(e[2], e[3], true);
        CE2(e[4], e[5], false); CE2(e[6], e[7], false);
        for (int k = 8; k <= 512; k <<= 1) {
            const bool d = ((l & (k >> 3)) == 0);
            for (int j = k >> 1; j >= 8; j >>= 1) {
                const int dl = j >> 3;
                const bool upper = (l & dl) != 0;
                #pragma unroll
                for (int q = 0; q < 8; ++q) {
                    u64 pv = __shfl_xor(e[q], dl);
                    u64 mx = e[q] > pv ? e[q] : pv;
                    u64 mn = e[q] > pv ? pv : e[q];
                    e[q] = (d != upper) ? mx : mn;
                }
            }
            CE2(e[0], e[4], d); CE2(e[1], e[5], d);
            CE2(e[2], e[6], d); CE2(e[3], e[7], d);
            CE2(e[0], e[2], d); CE2(e[1], e[3], d);
            CE2(e[4], e[6], d); CE2(e[5], e[7], d);
            CE2(e[0], e[1], d); CE2(e[2], e[3], d);
            CE2(e[4], e[5], d); CE2(e[6], e[7], d);
        }
        #undef CE2
        #pragma unroll
        for (int q = 0; q < 8; ++q) list[l * 8 + q] = e[q];
    }
    __syncthreads();

    float* out_s = out;                         // [B,300]
    float* out_b = out + B_IMG * K_TOT;         // [B,300,4]
    float* out_c = out + B_IMG * K_TOT * 5;     // [B,300]
    float* out_n = out + B_IMG * K_TOT * 6;     // [B]

    for (int i = tid; i < K_TOT; i += 1024) {
        u64 k = list[i];
        float s = funord((u32)(k >> 32));
        int flat = (M_SEL - 1) - (int)(u32)(k & 0xFFFFFFFFu);
        bool valid = s > (-5e29f);              // top_s > NEG/2
        float os = 0.0f, oc = 0.0f;
        float4 ob = make_float4(0.0f, 0.0f, 0.0f, 0.0f);
        if (valid && flat < NCAND) {
            int cc = flat / K_PER;
            int n  = ws_idx[base + flat];
            float4 bb = ((const float4*)boxes)[b * N_BOX + n];
            os = s;
            oc = (float)cc;
            ob.x = fminf(fmaxf(bb.x, 0.0f), 1.0f);
            ob.y = fminf(fmaxf(bb.y, 0.0f), 1.0f);
            ob.z = fminf(fmaxf(bb.z, 0.0f), 1.0f);
            ob.w = fminf(fmaxf(bb.w, 0.0f), 1.0f);
            atomicAdd(&sh_valid, 1);
        }
        out_s[b * K_TOT + i] = os;
        ((float4*)out_b)[b * K_TOT + i] = ob;
        out_c[b * K_TOT + i] = oc;
    }
    __syncthreads();
    if (tid == 0) out_n[b] = (float)sh_valid;
}

extern "C" void kernel_launch(void* const* d_in, const int* in_sizes, int n_in,
                              void* d_out, int out_size, void* d_ws, size_t ws_size,
                              hipStream_t stream) {
    const float* scores = (const float*)d_in[0];   // [4,1024,80]
    const float* boxes  = (const float*)d_in[1];   // [4,1024,1,4]

    char* ws = (char*)d_ws;                        // footprint unchanged
    float* ws_score = (float*)(ws + OFF_WSCORE);
    int*   ws_idx   = (int*)  (ws + OFF_WSIDX);

    nms_classes<<<dim3(B_IMG * C_CLS), dim3(256), 0, stream>>>(
        scores, boxes, ws_score, ws_idx);
    final_topk<<<dim3(B_IMG), dim3(1024), 0, stream>>>(
        ws_score, ws_idx, boxes, (float*)d_out);
}

// Round 4
// 117.031 us; speedup vs baseline: 1.2465x; 1.0338x over previous
//
#include <hip/hip_runtime.h>
#include <stdint.h>

#define N_BOX 1024
#define C_CLS 80
#define B_IMG 4
#define K_PER 100
#define K_TOT 300
#define NEGF  (-1e30f)
#define NCAND (C_CLS * K_PER)    // 8000 candidates per image
#define M_SEL 8192               // flat-index packing base for final top-k
#define KPAD  1088               // 1024 + 64 swizzle pad

// workspace layout (bytes) — unchanged proven offsets
#define OFF_WSCORE  1835008     // [B*C][K_PER] f32         128,000
#define OFF_WSIDX   1963008     // [B*C][K_PER] i32         128,000

typedef unsigned long long u64;
typedef unsigned int u32;

// LDS bank swizzle for u64 key array: bank16 rotates per 16-element group.
__device__ __forceinline__ int swz(int i) { return i + (i >> 4); }

// ---- monotone float <-> ordered-uint mapping (total order, bit-exact) ----
__device__ __forceinline__ u32 ford(float f) {
    u32 u = __float_as_uint(f);
    return (u & 0x80000000u) ? ~u : (u | 0x80000000u);
}
__device__ __forceinline__ float funord(u32 o) {
    u32 u = (o & 0x80000000u) ? (o ^ 0x80000000u) : ~o;
    return __uint_as_float(u);
}

// exact reference IoU>0.5 test (contract off, IEEE divide — proven bit-exact)
__device__ __forceinline__ bool iou_gt(float4 a, float aa, float4 b, float ab) {
#pragma clang fp contract(off)
    float ih = fminf(a.z, b.z) - fmaxf(a.x, b.x); ih = fmaxf(ih, 0.0f);
    float iw = fminf(a.w, b.w) - fmaxf(a.y, b.y); iw = fmaxf(iw, 0.0f);
    float inter = ih * iw;
    float uni = fmaxf(aa + ab - inter, 1e-12f);
    return (inter / uni) > 0.5f;
}

// ---------------------------------------------------------------------------
// Kernel 1 (r18): one block per (image, class), 256 thr, 4 waves.
// r17 post-mortem: VGPR=44 + dependent key->idx->bx LDS chains serialized the
// per-window IoU loops (~41 µs of exposed LDS latency). r18:
//  - window boxes double-buffered in wb[2][64]; NEXT window staged by wave 1
//    during the current window's compute (dependent chain hidden under VALU)
//  - all IoU loops read wb at compile-time offsets via explicit batch arrays
//    (wrow[16]/kbl[8]) -> independent wave-uniform broadcasts, deep MLP
//  - colk16[grp][me] has a unique writer (no init, no atomicOr); suppressed
//    mask via one __ballot per wave into sup64[grp]  -> 2 barriers/window
//  - greedy accept loop: r15-proven pure bit-ops shape, unchanged semantics
// ---------------------------------------------------------------------------
__global__ __launch_bounds__(256, 2) void nms_classes(
        const float* __restrict__ scores,   // [B, N, C]
        const float* __restrict__ boxes,    // [B, N, 1, 4]
        float* __restrict__ ws_score,       // [B*C*K_PER]
        int*   __restrict__ ws_idx)         // [B*C*K_PER]
{
    __shared__ u64    key[KPAD];            // 8704 B (swizzled)
    __shared__ float4 bx[N_BOX];            // canonical y1,x1,y2,x2 (16 KB)
    __shared__ float  ar[N_BOX];            // area (4 KB)
    __shared__ float4 wb[2][64];            // window boxes, double-buffered
    __shared__ float  wa[2][64];            // window areas
    __shared__ float4 kb[128];              // kept boxes (padded for batch-8)
    __shared__ float  ka[128];              // kept areas  (padded)
    __shared__ int    kept_t[K_PER];
    __shared__ u32    colk16[4][64];        // per-grp 16-bit kill rows
    __shared__ u64    sup64[4];             // per-wave suppressed ballots
    __shared__ int    sh_nvalid, sh_kept;

    const int tid  = threadIdx.x;
    const int lane = tid & 63;
    const int b  = blockIdx.x / C_CLS;
    const int c  = blockIdx.x % C_CLS;

    if (tid == 0) { sh_nvalid = 0; sh_kept = 0; }

    // ---- canonical boxes + areas into LDS ----
    for (int n = tid; n < N_BOX; n += 256) {
        float4 v = ((const float4*)boxes)[b * N_BOX + n];
        {
#pragma clang fp contract(off)
            float y1 = fminf(v.x, v.z), y2 = fmaxf(v.x, v.z);
            float x1 = fminf(v.y, v.w), x2 = fmaxf(v.y, v.w);
            bx[n] = make_float4(y1, x1, y2, x2);
            ar[n] = (y2 - y1) * (x2 - x1);
        }
    }
    __syncthreads();

    // ---- load scores: strided scalar reads (L2/L3-resident) ----
    u64 r[4];
    {
        const float* sc = scores + (size_t)(b * N_BOX) * C_CLS + c;
        int lv = 0;
        #pragma unroll
        for (int q = 0; q < 4; ++q) {
            int v = tid * 4 + q;
            float s0 = sc[(size_t)v * C_CLS];
            bool valid = s0 > 0.001f;                  // SCORE_THR
            float s = valid ? s0 : NEGF;
            r[q] = ((u64)ford(s) << 32) | (u32)(N_BOX - 1 - v);  // stable ties
            lv += valid ? 1 : 0;
        }
        if (lv) atomicAdd(&sh_nvalid, lv);
    }

    // ---- register/shuffle bitonic sort, descending (proven network) ----
    #define CE(a, b, d) { u64 _mx = (a) > (b) ? (a) : (b); \
                          u64 _mn = (a) > (b) ? (b) : (a); \
                          (a) = (d) ? _mx : _mn; (b) = (d) ? _mn : _mx; }
    CE(r[0], r[1], true); CE(r[2], r[3], false);

    for (int k = 4; k <= N_BOX; k <<= 1) {
        const bool d = ((tid & (k >> 2)) == 0);
        for (int j = k >> 1; j > 0; j >>= 1) {
            if (j >= 256) {                          // cross-wave: LDS stage
                __syncthreads();
                #pragma unroll
                for (int q = 0; q < 4; ++q) key[swz(tid * 4 + q)] = r[q];
                __syncthreads();
                const bool upper = ((tid * 4) & j) != 0;
                #pragma unroll
                for (int q = 0; q < 4; ++q) {
                    u64 pv = key[swz((tid * 4 + q) ^ j)];
                    u64 mx = r[q] > pv ? r[q] : pv;
                    u64 mn = r[q] > pv ? pv : r[q];
                    r[q] = (d != upper) ? mx : mn;
                }
            } else if (j >= 4) {                     // intra-wave: shuffle
                const int dl = j >> 2;
                const bool upper = (lane & dl) != 0;
                #pragma unroll
                for (int q = 0; q < 4; ++q) {
                    u64 pv = __shfl_xor(r[q], dl);
                    u64 mx = r[q] > pv ? r[q] : pv;
                    u64 mn = r[q] > pv ? pv : r[q];
                    r[q] = (d != upper) ? mx : mn;
                }
            } else if (j == 2) {
                CE(r[0], r[2], d); CE(r[1], r[3], d);
            } else {
                CE(r[0], r[1], d); CE(r[2], r[3], d);
            }
        }
    }
    #undef CE

    __syncthreads();
    #pragma unroll
    for (int q = 0; q < 4; ++q) key[swz(tid * 4 + q)] = r[q];
    __syncthreads();

    // ---- prologue: stage window 0's boxes (wave 0) ----
    if (tid < 64) {
        u64 kv = key[swz(tid)];
        int idx = (N_BOX - 1) - (int)(u32)(kv & 0xFFFFFFFFu);
        wb[0][tid] = bx[idx];
        wa[0][tid] = ar[idx];
    }

    const int nvalid = sh_nvalid;
    const int nwin = (nvalid + 63) >> 6;
    const int me  = tid & 63;               // candidate slot in window
    const int grp = tid >> 6;               // wave id 0..3

    for (int w = 0; w < nwin; ++w) {
        const int cur = w & 1;
        __syncthreads();                    // (A) staged boxes + kept stable
        if (sh_kept >= K_PER) break;        // wave-uniform
        const int kept0 = sh_kept;
        const int bt = w * 64;

        // stage NEXT window (wave 1) — dependent chain hides under IoU VALU
        if (grp == 1 && (w + 1) < nwin) {
            u64 kv = key[swz((bt + 64 + me) & (N_BOX - 1))];
            int idx = (N_BOX - 1) - (int)(u32)(kv & 0xFFFFFFFFu);
            wb[cur ^ 1][me] = bx[idx];
            wa[cur ^ 1][me] = ar[idx];
        }

        // my candidate (single independent broadcast-ish read)
        const float4 qm = wb[cur][me];
        const float  am = wa[cur][me];

        // intra-window kill rows grp*16..+15: batch-load then compute
        {
            float4 wrow[16]; float warow[16];
            #pragma unroll
            for (int rq = 0; rq < 16; ++rq) {
                wrow[rq]  = wb[cur][grp * 16 + rq];   // wave-uniform addr
                warow[rq] = wa[cur][grp * 16 + rq];
            }
            u32 bits = 0;
            #pragma unroll
            for (int rq = 0; rq < 16; ++rq) {
                int rr = grp * 16 + rq;
                bool kill = (rr != me) && iou_gt(wrow[rq], warow[rq], qm, am);
                bits |= ((u32)kill) << rq;
            }
            colk16[grp][me] = bits;                   // unique writer
        }

        // cross-window vs kept list: strided over waves, batch-8 loads
        {
            bool supme = false;
            for (int t0 = 0; grp + 4 * t0 < kept0; t0 += 8) {
                float4 kbl[8]; float kal[8];
                #pragma unroll
                for (int i = 0; i < 8; ++i) {
                    int k = grp + 4 * (t0 + i);       // <= 127, padded
                    kbl[i] = kb[k]; kal[i] = ka[k];
                }
                #pragma unroll
                for (int i = 0; i < 8; ++i) {
                    int k = grp + 4 * (t0 + i);
                    if (k < kept0 && iou_gt(kbl[i], kal[i], qm, am)) supme = true;
                }
            }
            u64 bal = __ballot(supme);
            if (lane == 0) sup64[grp] = bal;
        }
        __syncthreads();                    // (C) masks ready

        // greedy accept loop: wave 0 only, pure bit ops (r15-proven shape)
        if (grp == 0) {
            u32 c0 = colk16[0][lane], c1 = colk16[1][lane];
            u32 c2 = colk16[2][lane], c3 = colk16[3][lane];
            u64 colkill = (u64)c0 | ((u64)c1 << 16)
                        | ((u64)c2 << 32) | ((u64)c3 << 48);
            u64 supp = sup64[0] | sup64[1] | sup64[2] | sup64[3];
            bool in = ((bt + lane) < nvalid) && !((supp >> lane) & 1ull);
            u64 pending = __ballot(in);
            int kept = kept0;
            while (pending && kept < K_PER) {
                int t0 = __ffsll((long long)pending) - 1;   // wave-uniform
                if (lane == 0) kept_t[kept] = bt + t0;
                if (lane == t0) { kb[kept] = qm; ka[kept] = am; }
                kept++;
                bool kill = (colkill >> t0) & 1ull;
                pending &= ~(1ull << t0);
                pending &= ~__ballot(kill);
            }
            if (lane == 0) sh_kept = kept;
        }
    }
    __syncthreads();

    const int kept = sh_kept;
    if (tid < K_PER) {
        int ob = (b * C_CLS + c) * K_PER + tid;
        if (tid < kept) {
            u64 k = key[swz(kept_t[tid])];
            ws_score[ob] = funord((u32)(k >> 32));
            ws_idx[ob]   = (N_BOX - 1) - (int)(u32)(k & 0xFFFFFFFFu);
        } else {
            ws_score[ob] = NEGF;
            ws_idx[ob]   = 0;
        }
    }
}

// ---------------------------------------------------------------------------
// Kernel 2: final top-300 per image (proven verbatim).
// ---------------------------------------------------------------------------
__global__ __launch_bounds__(1024) void final_topk(
        const float* __restrict__ ws_score,
        const int*   __restrict__ ws_idx,
        const float* __restrict__ boxes,    // [B, N, 1, 4]
        float* __restrict__ out)
{
    __shared__ u32 skey[NCAND];             // 32 KB
    __shared__ u32 hist4[256 * 4];          // 4 KB
    __shared__ u64 list[512];
    __shared__ int sh_sel;
    __shared__ u32 sh_need;
    __shared__ int sh_cnt, sh_valid;

    const int tid = threadIdx.x;
    const int b = blockIdx.x;
    const int base = b * NCAND;

    if (tid == 0) { sh_cnt = 0; sh_valid = 0; }
    for (int i = tid; i < NCAND; i += 1024)
        skey[i] = ford(ws_score[base + i]);
    if (tid < 512) list[tid] = 0;
    hist4[tid] = 0;
    __syncthreads();

    u64 prefix = 0;
    u32 need = K_TOT;
    const int rounds[6] = {7, 6, 5, 4, 1, 0};
    const int slot = tid & 3;

    for (int rd = 0; rd < 6; ++rd) {
        const int d = rounds[rd];
        for (int i = tid; i < NCAND; i += 1024) {
            u64 k = ((u64)skey[i] << 32) | (u32)(M_SEL - 1 - i);
            // d==7 guard: shift by 64 is UB (the round-3/4 crash)
            bool match = (d == 7) || (((k ^ prefix) >> (8 * (d + 1))) == 0);
            if (match)
                atomicAdd(&hist4[(((u32)(k >> (8 * d)) & 0xFFu) << 2) | slot], 1u);
        }
        __syncthreads();
        if (tid < 64) {
            const int l = tid;
            u32 h[4];
            #pragma unroll
            for (int q = 0; q < 4; ++q) {
                int bin = 4 * l + q;
                h[q] = hist4[bin * 4 + 0] + hist4[bin * 4 + 1]
                     + hist4[bin * 4 + 2] + hist4[bin * 4 + 3];
                hist4[bin * 4 + 0] = 0; hist4[bin * 4 + 1] = 0;
                hist4[bin * 4 + 2] = 0; hist4[bin * 4 + 3] = 0;
            }
            u32 s3 = h[3], s2 = h[2] + s3, s1 = h[1] + s2, s0 = h[0] + s1;
            u32 tot = s0, S = tot;
            #pragma unroll
            for (int off = 1; off < 64; off <<= 1) {
                u32 t = __shfl(S, (l + off) & 63);
                if (l + off < 64) S += t;
            }
            u32 T = S - tot;
            u32 sv0 = s0 + T, sv1 = s1 + T, sv2 = s2 + T, sv3 = s3 + T;
            if (sv0 >= need && sv1 < need) { sh_sel = 4*l;     sh_need = need - sv1; }
            if (sv1 >= need && sv2 < need) { sh_sel = 4*l + 1; sh_need = need - sv2; }
            if (sv2 >= need && sv3 < need) { sh_sel = 4*l + 2; sh_need = need - sv3; }
            if (sv3 >= need && T   < need) { sh_sel = 4*l + 3; sh_need = need - T;   }
        }
        __syncthreads();
        prefix |= ((u64)(u32)sh_sel) << (8 * d);
        need = sh_need;
        __syncthreads();
    }

    for (int i = tid; i < NCAND; i += 1024) {
        u64 k = ((u64)skey[i] << 32) | (u32)(M_SEL - 1 - i);
        if (k >= prefix) {
            int p = atomicAdd(&sh_cnt, 1);
            if (p < 512) list[p] = k;
        }
    }
    __syncthreads();

    // one-wave register bitonic sort of list[512], descending (pads 0 last)
    if (tid < 64) {
        const int l = tid;
        u64 e[8];
        #pragma unroll
        for (int q = 0; q < 8; ++q) e[q] = list[l * 8 + q];
        #define CE2(a, b, dd) { u64 _mx = (a) > (b) ? (a) : (b); \
                                u64 _mn = (a) > (b) ? (b) : (a); \
                                (a) = (dd) ? _mx : _mn; (b) = (dd) ? _mn : _mx; }
        CE2(e[0], e[1], true);  CE2(e[2], e[3], false);
        CE2(e[4], e[5], true);  CE2(e[6], e[7], false);
        CE2(e[0], e[2], true);  CE2(e[1], e[3], true);
        CE2(e[4], e[6], false); CE2(e[5], e[7], false);
        CE2(e[0], e[1], true);  CE2(e[2], e[3], true);
        CE2(e[4], e[5], false); CE2(e[6], e[7], false);
        for (int k = 8; k <= 512; k <<= 1) {
            const bool d = ((l & (k >> 3)) == 0);
            for (int j = k >> 1; j >= 8; j >>= 1) {
                const int dl = j >> 3;
                const bool upper = (l & dl) != 0;
                #pragma unroll
                for (int q = 0; q < 8; ++q) {
                    u64 pv = __shfl_xor(e[q], dl);
                    u64 mx = e[q] > pv ? e[q] : pv;
                    u64 mn = e[q] > pv ? pv : e[q];
                    e[q] = (d != upper) ? mx : mn;
                }
            }
            CE2(e[0], e[4], d); CE2(e[1], e[5], d);
            CE2(e[2], e[6], d); CE2(e[3], e[7], d);
            CE2(e[0], e[2], d); CE2(e[1], e[3], d);
            CE2(e[4], e[6], d); CE2(e[5], e[7], d);
            CE2(e[0], e[1], d); CE2(e[2], e[3], d);
            CE2(e[4], e[5], d); CE2(e[6], e[7], d);
        }
        #undef CE2
        #pragma unroll
        for (int q = 0; q < 8; ++q) list[l * 8 + q] = e[q];
    }
    __syncthreads();

    float* out_s = out;                         // [B,300]
    float* out_b = out + B_IMG * K_TOT;         // [B,300,4]
    float* out_c = out + B_IMG * K_TOT * 5;     // [B,300]
    float* out_n = out + B_IMG * K_TOT * 6;     // [B]

    for (int i = tid; i < K_TOT; i += 1024) {
        u64 k = list[i];
        float s = funord((u32)(k >> 32));
        int flat = (M_SEL - 1) - (int)(u32)(k & 0xFFFFFFFFu);
        bool valid = s > (-5e29f);              // top_s > NEG/2
        float os = 0.0f, oc = 0.0f;
        float4 ob = make_float4(0.0f, 0.0f, 0.0f, 0.0f);
        if (valid && flat < NCAND) {
            int cc = flat / K_PER;
            int n  = ws_idx[base + flat];
            float4 bb = ((const float4*)boxes)[b * N_BOX + n];
            os = s;
            oc = (float)cc;
            ob.x = fminf(fmaxf(bb.x, 0.0f), 1.0f);
            ob.y = fminf(fmaxf(bb.y, 0.0f), 1.0f);
            ob.z = fminf(fmaxf(bb.z, 0.0f), 1.0f);
            ob.w = fminf(fmaxf(bb.w, 0.0f), 1.0f);
            atomicAdd(&sh_valid, 1);
        }
        out_s[b * K_TOT + i] = os;
        ((float4*)out_b)[b * K_TOT + i] = ob;
        out_c[b * K_TOT + i] = oc;
    }
    __syncthreads();
    if (tid == 0) out_n[b] = (float)sh_valid;
}

extern "C" void kernel_launch(void* const* d_in, const int* in_sizes, int n_in,
                              void* d_out, int out_size, void* d_ws, size_t ws_size,
                              hipStream_t stream) {
    const float* scores = (const float*)d_in[0];   // [4,1024,80]
    const float* boxes  = (const float*)d_in[1];   // [4,1024,1,4]

    char* ws = (char*)d_ws;                        // footprint unchanged
    float* ws_score = (float*)(ws + OFF_WSCORE);
    int*   ws_idx   = (int*)  (ws + OFF_WSIDX);

    nms_classes<<<dim3(B_IMG * C_CLS), dim3(256), 0, stream>>>(
        scores, boxes, ws_score, ws_idx);
    final_topk<<<dim3(B_IMG), dim3(1024), 0, stream>>>(
        ws_score, ws_idx, boxes, (float*)d_out);
}